// Round 1
// baseline (307.752 us; speedup 1.0000x reference)
//
#include <hip/hip_runtime.h>

#define NEGF -1.0e30f

// logaddexp: exact pass-through when one side is NEG (-1e30), matches jnp.logaddexp
__device__ __forceinline__ float lae(float a, float b) {
    float mx = fmaxf(a, b);
    float mn = fminf(a, b);
    return mx + __logf(1.0f + __expf(mn - mx));
}

// Kernel 1: per-row logsumexp over C=128 logits. One 64-lane wave per row,
// 4 rows per 256-thread block. Writes lse[b*T+t].
__global__ __launch_bounds__(256) void lse_rows(const float* __restrict__ yp,
                                                float* __restrict__ lse,
                                                int nrows) {
    int row  = blockIdx.x * 4 + (threadIdx.x >> 6);
    int lane = threadIdx.x & 63;
    if (row >= nrows) return;
    const float2 v = *reinterpret_cast<const float2*>(yp + (size_t)row * 128 + lane * 2);
    float m = fmaxf(v.x, v.y);
    #pragma unroll
    for (int off = 32; off > 0; off >>= 1) m = fmaxf(m, __shfl_xor(m, off, 64));
    float s = __expf(v.x - m) + __expf(v.y - m);
    #pragma unroll
    for (int off = 32; off > 0; off >>= 1) s += __shfl_xor(s, off, 64);
    if (lane == 0) lse[row] = m + __logf(s);
}

// Kernel 2: alpha recursion on RAW logits (shift-invariance of logaddexp),
// one block per batch element. 257 states on 256 threads; logits double-
// buffered in LDS with register prefetch; ONE barrier per time step.
__global__ __launch_bounds__(256) void ctc_alpha(const int* __restrict__ yt,
                                                 const float* __restrict__ yp,
                                                 const float* __restrict__ lse,
                                                 float* __restrict__ loss) {
    constexpr int T = 512, C = 128, L = 128, S = 257, BLANK = 127;
    const int b   = blockIdx.x;
    const int tid = threadIdx.x;

    __shared__ int           ext[S];
    __shared__ unsigned char skip[S];
    __shared__ float         A[2][S];
    __shared__ float         X[2][C];
    __shared__ float         red[256];

    // Build extended label sequence: ext[2k]=blank, ext[2k+1]=label_k
    int lab = 0;
    if (tid < L) {
        lab = yt[b * L + tid];
        ext[2 * tid + 1] = lab;
    }
    if (tid <= L) ext[2 * tid] = BLANK;
    for (int s = tid; s < S; s += 256) { skip[s] = 0; A[0][s] = NEGF; }
    __syncthreads();
    // skip allowed at odd s>=3 when adjacent labels differ
    if (tid >= 1 && tid < L) skip[2 * tid + 1] = (ext[2 * tid + 1] != ext[2 * tid - 1]) ? 1 : 0;
    // label length = #nonzero labels (barrier semantics cover skip[] writes)
    const int llen = __syncthreads_count((tid < L) && (lab != 0));

    // alpha_0 (raw logits) + preload x_1 into X[1]
    if (tid < C) X[1][tid] = yp[((size_t)b * T + 1) * C + tid];
    if (tid == 0) A[0][0] = yp[((size_t)b * T) * C + BLANK];
    if (tid == 1) A[0][1] = yp[((size_t)b * T) * C + ext[1]];
    __syncthreads();

    for (int t = 1; t < T; ++t) {
        const int cp = (t - 1) & 1, cn = t & 1;
        float rx = 0.0f;
        const bool pf = (tid < C) && (t + 1 < T);
        if (pf) rx = yp[((size_t)b * T + t + 1) * C + tid];   // prefetch x_{t+1}

        #pragma unroll
        for (int s = tid; s < S; s += 256) {
            float a0 = A[cp][s];
            float a1 = (s >= 1) ? A[cp][s - 1] : NEGF;
            float a2 = skip[s] ? A[cp][s - 2] : NEGF;
            float comb = lae(lae(a0, a1), a2);
            A[cn][s] = comb + X[cn][ext[s]];   // X[t&1] holds x_t
        }
        if (pf) X[(t + 1) & 1][tid] = rx;
        __syncthreads();   // single barrier per step (double-buffered A and X)
    }

    // deterministic sum of the 512 per-row lse values for this batch
    red[tid] = lse[(size_t)b * T + tid] + lse[(size_t)b * T + 256 + tid];
    __syncthreads();
    for (int off = 128; off > 0; off >>= 1) {
        if (tid < off) red[tid] += red[tid + off];
        __syncthreads();
    }

    if (tid == 0) {
        const int l = llen;                 // l >= 64 by construction
        float fa = A[(T - 1) & 1][2 * l];
        float fb = A[(T - 1) & 1][2 * l - 1];
        loss[b] = -(lae(fa, fb) - red[0]);
    }
}

// Kernel 3: deterministic mean over B=256 losses
__global__ __launch_bounds__(256) void finalize(const float* __restrict__ loss,
                                                float* __restrict__ out) {
    __shared__ float red[256];
    const int tid = threadIdx.x;
    red[tid] = loss[tid];
    __syncthreads();
    for (int off = 128; off > 0; off >>= 1) {
        if (tid < off) red[tid] += red[tid + off];
        __syncthreads();
    }
    if (tid == 0) out[0] = red[0] * (1.0f / 256.0f);
}

extern "C" void kernel_launch(void* const* d_in, const int* in_sizes, int n_in,
                              void* d_out, int out_size, void* d_ws, size_t ws_size,
                              hipStream_t stream) {
    constexpr int B = 256, T = 512;
    const int*   y_true = (const int*)d_in[0];
    const float* y_pred = (const float*)d_in[1];
    float* out  = (float*)d_out;
    float* lse  = (float*)d_ws;        // B*T floats
    float* loss = lse + (size_t)B * T; // B floats

    lse_rows<<<(B * T) / 4, 256, 0, stream>>>(y_pred, lse, B * T);
    ctc_alpha<<<B, 256, 0, stream>>>(y_true, y_pred, lse, loss);
    finalize<<<1, 256, 0, stream>>>(loss, out);
}

// Round 2
// 64.834 us; speedup vs baseline: 4.7468x; 4.7468x over previous
//
#include <hip/hip_runtime.h>

#define LN2F 0.69314718055994530942f

// lane l gets lane l-1's v; lane 0 gets fill. VALU-latency shift (no LDS).
__device__ __forceinline__ float shr1(float v, float fill) {
#if __has_builtin(__builtin_amdgcn_update_dpp)
    return __int_as_float(__builtin_amdgcn_update_dpp(
        __float_as_int(fill), __float_as_int(v), 0x138 /*wave_shr:1*/, 0xF, 0xF, false));
#else
    float r = __shfl_up(v, 1, 64);
    return (threadIdx.x & 63) ? r : fill;
#endif
}

// Kernel 1: per-row logsumexp over C=128 logits. One 64-lane wave per row,
// 4 rows per 256-thread block. Writes lse[b*T+t].
__global__ __launch_bounds__(256) void lse_rows(const float* __restrict__ yp,
                                                float* __restrict__ lse,
                                                int nrows) {
    int row  = blockIdx.x * 4 + (threadIdx.x >> 6);
    int lane = threadIdx.x & 63;
    if (row >= nrows) return;
    const float2 v = *reinterpret_cast<const float2*>(yp + (size_t)row * 128 + lane * 2);
    float m = fmaxf(v.x, v.y);
    #pragma unroll
    for (int off = 32; off > 0; off >>= 1) m = fmaxf(m, __shfl_xor(m, off, 64));
    float s = __expf(v.x - m) + __expf(v.y - m);
    #pragma unroll
    for (int off = 32; off > 0; off >>= 1) s += __shfl_xor(s, off, 64);
    if (lane == 0) lse[row] = m + __logf(s);
}

// Kernel 2: alpha recursion, ONE WAVE per batch element, linear domain with
// blank-shift (2 exps/step), power-of-2 renorm every 32 steps, 8-deep
// register-ring prefetch of the 3 per-lane emission gathers. No barriers.
__global__ __launch_bounds__(64) void ctc_alpha(const int* __restrict__ yt,
                                                const float* __restrict__ yp,
                                                const float* __restrict__ lse,
                                                float* __restrict__ loss) {
    constexpr int T = 512, C = 128, L = 128, BLANK = 127;
    constexpr int PF = 8;
    const int b    = blockIdx.x;
    const int lane = threadIdx.x;

    const float* xb = yp + (size_t)b * T * C;

    // this lane's odd-state label classes (time-invariant)
    const int c1 = yt[b * L + 2 * lane];
    const int c3 = yt[b * L + 2 * lane + 1];
    const int cp = (lane > 0) ? yt[b * L + 2 * lane - 1] : -1;
    const float sk1 = (lane > 0 && c1 != cp) ? 1.0f : 0.0f;  // skip into s=4l+1
    const float sk3 = (c3 != c1) ? 1.0f : 0.0f;              // skip into s=4l+3

    const int llen = __popcll(__ballot(c1 != 0)) + __popcll(__ballot(c3 != 0));

    const float* p1 = xb + c1;
    const float* p3 = xb + c3;
    const float* pb = xb + BLANK;

    float r1[PF], r3[PF], rb[PF];
    #pragma unroll
    for (int i = 0; i < PF; ++i) {
        r1[i] = p1[i * C];
        r3[i] = p3[i * C];
        rb[i] = pb[i * C];
    }

    // states: lane l owns s=4l..4l+3 in o0..o3; lane 63 also s=256 in o4
    float o0, o1, o2, o3, o4;
    float Sb;        // sum over t of x_t[blank] (uniform across lanes)
    int   Eacc = 0;  // sum of renorm exponents

    {   // t = 0 init (beta_0 = exp(alpha_0 - x_0[blank]))
        const float x_b = rb[0];
        o0 = (lane == 0) ? 1.0f : 0.0f;
        o1 = (lane == 0) ? __expf(r1[0] - x_b) : 0.0f;
        o2 = 0.0f; o3 = 0.0f; o4 = 0.0f;
        Sb = x_b;
    }

#define STEP(t_, slot_, pf_)                                               \
    {                                                                      \
        const float x_b = rb[slot_];                                       \
        const float e1  = __expf(r1[slot_] - x_b);                         \
        const float e3  = __expf(r3[slot_] - x_b);                         \
        if (pf_) {                                                         \
            r1[slot_] = p1[((t_) + PF) * C];                               \
            r3[slot_] = p3[((t_) + PF) * C];                               \
            rb[slot_] = pb[((t_) + PF) * C];                               \
        }                                                                  \
        const float pm = shr1(o3, 0.0f);                                   \
        const float n0 = o0 + pm;                                          \
        const float n1 = (o1 + o0 + sk1 * pm) * e1;                        \
        const float n2 = o2 + o1;                                          \
        const float n3 = (o3 + o2 + sk3 * o1) * e3;                        \
        o4 = o4 + o3;                                                      \
        o0 = n0; o1 = n1; o2 = n2; o3 = n3;                                \
        Sb += x_b;                                                         \
        if (((t_) & 31) == 0) {                                            \
            float m_ = fmaxf(fmaxf(fmaxf(o0, o1), fmaxf(o2, o3)), o4);     \
            m_ = fmaxf(m_, __shfl_xor(m_, 32, 64));                        \
            m_ = fmaxf(m_, __shfl_xor(m_, 16, 64));                        \
            m_ = fmaxf(m_, __shfl_xor(m_, 8, 64));                         \
            m_ = fmaxf(m_, __shfl_xor(m_, 4, 64));                         \
            m_ = fmaxf(m_, __shfl_xor(m_, 2, 64));                         \
            m_ = fmaxf(m_, __shfl_xor(m_, 1, 64));                         \
            const int ie_ = (__float_as_int(m_) >> 23) & 0xFF;             \
            const float sc_ = __int_as_float((253 - ie_) << 23);           \
            o0 *= sc_; o1 *= sc_; o2 *= sc_; o3 *= sc_; o4 *= sc_;         \
            Eacc += ie_ - 126;                                             \
        }                                                                  \
    }

    // main: t = 1..496, always prefetch (t+8 <= 504 < 512)
    for (int tb = 1; tb <= 489; tb += 8) {
        #pragma unroll
        for (int j = 0; j < 8; ++j)
            STEP(tb + j, (1 + j) & 7, true);
    }
    // mid: t = 497..503, prefetch 505..511
    #pragma unroll
    for (int t = 497; t < 504; ++t)
        STEP(t, t & 7, true);
    // tail: t = 504..511, no prefetch
    #pragma unroll
    for (int t = 504; t < 512; ++t)
        STEP(t, t & 7, false);
#undef STEP

    // epilogue: publish states, reduce lse, compute loss on lane 0
    __shared__ float Af[257];
    Af[4 * lane + 0] = o0; Af[4 * lane + 1] = o1;
    Af[4 * lane + 2] = o2; Af[4 * lane + 3] = o3;
    if (lane == 63) Af[256] = o4;

    const float* lrow = lse + (size_t)b * T + lane * 8;
    const float4 la = *reinterpret_cast<const float4*>(lrow);
    const float4 lc = *reinterpret_cast<const float4*>(lrow + 4);
    float ls = ((la.x + la.y) + (la.z + la.w)) + ((lc.x + lc.y) + (lc.z + lc.w));
    #pragma unroll
    for (int off = 32; off > 0; off >>= 1) ls += __shfl_xor(ls, off, 64);

    __syncthreads();
    if (lane == 0) {
        const float fa = Af[2 * llen];
        const float fb = Af[2 * llen - 1];
        loss[b] = -(__logf(fa + fb) + Sb + (float)Eacc * LN2F - ls);
    }
}

// Kernel 3: deterministic mean over B=256 losses
__global__ __launch_bounds__(256) void finalize(const float* __restrict__ loss,
                                                float* __restrict__ out) {
    __shared__ float red[256];
    const int tid = threadIdx.x;
    red[tid] = loss[tid];
    __syncthreads();
    for (int off = 128; off > 0; off >>= 1) {
        if (tid < off) red[tid] += red[tid + off];
        __syncthreads();
    }
    if (tid == 0) out[0] = red[0] * (1.0f / 256.0f);
}

extern "C" void kernel_launch(void* const* d_in, const int* in_sizes, int n_in,
                              void* d_out, int out_size, void* d_ws, size_t ws_size,
                              hipStream_t stream) {
    constexpr int B = 256, T = 512;
    const int*   y_true = (const int*)d_in[0];
    const float* y_pred = (const float*)d_in[1];
    float* out  = (float*)d_out;
    float* lse  = (float*)d_ws;        // B*T floats
    float* loss = lse + (size_t)B * T; // B floats

    lse_rows<<<(B * T) / 4, 256, 0, stream>>>(y_pred, lse, B * T);
    ctc_alpha<<<B, 64, 0, stream>>>(y_true, y_pred, lse, loss);
    finalize<<<1, 256, 0, stream>>>(loss, out);
}

// Round 3
// 58.338 us; speedup vs baseline: 5.2753x; 1.1114x over previous
//
#include <hip/hip_runtime.h>
#include <hip/hip_fp16.h>

#define LN2F 0.69314718055994530942f

// lane l gets lane l-1's v; lane 0 gets fill. VALU-latency shift (no LDS).
__device__ __forceinline__ float shr1(float v, float fill) {
#if __has_builtin(__builtin_amdgcn_update_dpp)
    return __int_as_float(__builtin_amdgcn_update_dpp(
        __float_as_int(fill), __float_as_int(v), 0x138 /*wave_shr:1*/, 0xF, 0xF, false));
#else
    float r = __shfl_up(v, 1, 64);
    return (threadIdx.x & 63) ? r : fill;
#endif
}

// Kernel 1 (prep): one 64-lane wave per (b,t) row, 4 rows/block.
//  - logsumexp of the row  -> lsb[row] = lse - x[blank]
//  - in-register gather of this b's label logits via cross-lane shuffles:
//      G[row][lane] = half2( x[c1(lane)]-x[blank], x[c3(lane)]-x[blank] )
// so the serial kernel needs ONE coalesced dword per lane per step.
__global__ __launch_bounds__(256) void prep(const int* __restrict__ yt,
                                            const float* __restrict__ yp,
                                            float* __restrict__ lsb,
                                            __half2* __restrict__ G,
                                            int nrows) {
    const int row  = blockIdx.x * 4 + (threadIdx.x >> 6);
    const int lane = threadIdx.x & 63;
    if (row >= nrows) return;
    const int b = row >> 9;                      // T = 512
    const float2 v = *reinterpret_cast<const float2*>(yp + (size_t)row * 128 + lane * 2);

    // logsumexp over the 128 classes (butterfly -> all lanes hold result)
    float m = fmaxf(v.x, v.y);
    #pragma unroll
    for (int off = 32; off > 0; off >>= 1) m = fmaxf(m, __shfl_xor(m, off, 64));
    float s = __expf(v.x - m) + __expf(v.y - m);
    #pragma unroll
    for (int off = 32; off > 0; off >>= 1) s += __shfl_xor(s, off, 64);
    const float lse = m + __logf(s);

    const float xb = __shfl(v.y, 63, 64);        // x[127] = blank logit

    // this lane's two label classes for batch b
    const int c1 = yt[b * 128 + 2 * lane];
    const int c3 = yt[b * 128 + 2 * lane + 1];

    // gather x[c]: element c lives in lane c>>1, component c&1
    const float a_lo = __shfl(v.x, c1 >> 1, 64);
    const float a_hi = __shfl(v.y, c1 >> 1, 64);
    const float x1 = (c1 & 1) ? a_hi : a_lo;
    const float b_lo = __shfl(v.x, c3 >> 1, 64);
    const float b_hi = __shfl(v.y, c3 >> 1, 64);
    const float x3 = (c3 & 1) ? b_hi : b_lo;

    G[(size_t)row * 64 + lane] = __floats2half2_rn(x1 - xb, x3 - xb);
    if (lane == 0) lsb[row] = lse - xb;
}

// Kernel 2: alpha recursion, ONE WAVE per batch element, linear domain with
// blank-shift (2 exps/step), power-of-2 renorm every 32 steps. Per step:
// one coalesced half2 load from G (ring depth 16). No barriers in the loop.
__global__ __launch_bounds__(64) void ctc_alpha(const int* __restrict__ yt,
                                                const __half2* __restrict__ G,
                                                const float* __restrict__ lsb,
                                                float* __restrict__ loss) {
    constexpr int T = 512, L = 128;
    constexpr int PF = 16;
    const int b    = blockIdx.x;
    const int lane = threadIdx.x;

    const int c1 = yt[b * L + 2 * lane];
    const int c3 = yt[b * L + 2 * lane + 1];
    const int cp = (lane > 0) ? yt[b * L + 2 * lane - 1] : -1;
    const float sk1 = (lane > 0 && c1 != cp) ? 1.0f : 0.0f;
    const float sk3 = (c3 != c1) ? 1.0f : 0.0f;
    const int llen = __popcll(__ballot(c1 != 0)) + __popcll(__ballot(c3 != 0));

    const __half2* g = G + (size_t)b * T * 64 + lane;   // step stride: 64 half2 = 256 B/wave

    __half2 rg[PF];
    #pragma unroll
    for (int i = 0; i < PF; ++i) rg[i] = g[i * 64];

    // states: lane l owns s=4l..4l+3 in o0..o3; lane 63 also s=256 in o4
    float o0, o1, o2, o3, o4;
    int   Eacc = 0;

    {   // t = 0: beta_0 = exp(alpha_0 - x_0[blank])
        const float2 d = __half22float2(rg[0]);
        o0 = (lane == 0) ? 1.0f : 0.0f;
        o1 = (lane == 0) ? __expf(d.x) : 0.0f;
        o2 = 0.0f; o3 = 0.0f; o4 = 0.0f;
    }

#define STEP(t_, slot_, pf_)                                               \
    {                                                                      \
        const float2 d_ = __half22float2(rg[slot_]);                       \
        const float e1  = __expf(d_.x);                                    \
        const float e3  = __expf(d_.y);                                    \
        if (pf_) rg[slot_] = g[((t_) + PF) * 64];                          \
        const float pm = shr1(o3, 0.0f);                                   \
        const float n0 = o0 + pm;                                          \
        const float n1 = (o1 + o0 + sk1 * pm) * e1;                        \
        const float n2 = o2 + o1;                                          \
        const float n3 = (o3 + o2 + sk3 * o1) * e3;                        \
        o4 = o4 + o3;                                                      \
        o0 = n0; o1 = n1; o2 = n2; o3 = n3;                                \
        if (((t_) & 31) == 0) {                                            \
            float m_ = fmaxf(fmaxf(fmaxf(o0, o1), fmaxf(o2, o3)), o4);     \
            m_ = fmaxf(m_, __shfl_xor(m_, 32, 64));                        \
            m_ = fmaxf(m_, __shfl_xor(m_, 16, 64));                        \
            m_ = fmaxf(m_, __shfl_xor(m_, 8, 64));                         \
            m_ = fmaxf(m_, __shfl_xor(m_, 4, 64));                         \
            m_ = fmaxf(m_, __shfl_xor(m_, 2, 64));                         \
            m_ = fmaxf(m_, __shfl_xor(m_, 1, 64));                         \
            const int ie_ = (__float_as_int(m_) >> 23) & 0xFF;             \
            const float sc_ = __int_as_float((253 - ie_) << 23);           \
            o0 *= sc_; o1 *= sc_; o2 *= sc_; o3 *= sc_; o4 *= sc_;         \
            Eacc += ie_ - 126;                                             \
        }                                                                  \
    }

    // main: t = 1..480 in blocks of 16, always prefetching t+16 (<= 496)
    for (int tb = 1; tb <= 465; tb += 16) {
        #pragma unroll
        for (int j = 0; j < 16; ++j)
            STEP(tb + j, (tb + j) & (PF - 1), true);
    }
    // t = 481..495: prefetch 497..511
    #pragma unroll
    for (int t = 481; t < 496; ++t)
        STEP(t, t & (PF - 1), true);
    // t = 496..511: drain, no prefetch
    #pragma unroll
    for (int t = 496; t < 512; ++t)
        STEP(t, t & (PF - 1), false);
#undef STEP

    // epilogue: publish states, reduce (lse - x_blank), finish on lane 0
    __shared__ float Af[257];
    Af[4 * lane + 0] = o0; Af[4 * lane + 1] = o1;
    Af[4 * lane + 2] = o2; Af[4 * lane + 3] = o3;
    if (lane == 63) Af[256] = o4;

    const float* lrow = lsb + (size_t)b * T + lane * 8;
    const float4 la = *reinterpret_cast<const float4*>(lrow);
    const float4 lc = *reinterpret_cast<const float4*>(lrow + 4);
    float ls = ((la.x + la.y) + (la.z + la.w)) + ((lc.x + lc.y) + (lc.z + lc.w));
    #pragma unroll
    for (int off = 32; off > 0; off >>= 1) ls += __shfl_xor(ls, off, 64);

    __syncthreads();
    if (lane == 0) {
        const float fa = Af[2 * llen];
        const float fb = Af[2 * llen - 1];
        loss[b] = -(__logf(fa + fb) + (float)Eacc * LN2F - ls);
    }
}

// Kernel 3: deterministic mean over B=256 losses
__global__ __launch_bounds__(256) void finalize(const float* __restrict__ loss,
                                                float* __restrict__ out) {
    __shared__ float red[256];
    const int tid = threadIdx.x;
    red[tid] = loss[tid];
    __syncthreads();
    for (int off = 128; off > 0; off >>= 1) {
        if (tid < off) red[tid] += red[tid + off];
        __syncthreads();
    }
    if (tid == 0) out[0] = red[0] * (1.0f / 256.0f);
}

extern "C" void kernel_launch(void* const* d_in, const int* in_sizes, int n_in,
                              void* d_out, int out_size, void* d_ws, size_t ws_size,
                              hipStream_t stream) {
    constexpr int B = 256, T = 512;
    const int*   y_true = (const int*)d_in[0];
    const float* y_pred = (const float*)d_in[1];
    float* out  = (float*)d_out;

    float*   lsb  = (float*)d_ws;                    // B*T floats
    float*   loss = lsb + (size_t)B * T;             // B floats
    __half2* G    = (__half2*)(loss + B);            // B*T*64 half2 (33.5 MB)

    prep<<<(B * T) / 4, 256, 0, stream>>>(y_true, y_pred, lsb, G, B * T);
    ctc_alpha<<<B, 64, 0, stream>>>(y_true, G, lsb, loss);
    finalize<<<1, 256, 0, stream>>>(loss, out);
}

// Round 4
// 48.302 us; speedup vs baseline: 6.3714x; 1.2078x over previous
//
#include <hip/hip_runtime.h>
#include <hip/hip_fp16.h>

#define LN2F 0.69314718055994530942f

// lane l gets lane l-1's v; lane 0 gets fill. VALU DPP, no LDS.
__device__ __forceinline__ float shr1(float v, float fill) {
    return __int_as_float(__builtin_amdgcn_update_dpp(
        __float_as_int(fill), __float_as_int(v), 0x138 /*wave_shr:1*/, 0xF, 0xF, false));
}

// Classic GCN DPP wave-reduce: row_shr 1,2,4,8 then bcast15(0xA), bcast31(0xC).
// Result valid in lane 63 only. All VALU pipe (no ds_bpermute).
__device__ __forceinline__ float wave_max63(float x) {
    int iv = __float_as_int(x); int t;
    t = __builtin_amdgcn_update_dpp(iv, iv, 0x111, 0xF, 0xF, false);
    x = fmaxf(x, __int_as_float(t)); iv = __float_as_int(x);
    t = __builtin_amdgcn_update_dpp(iv, iv, 0x112, 0xF, 0xF, false);
    x = fmaxf(x, __int_as_float(t)); iv = __float_as_int(x);
    t = __builtin_amdgcn_update_dpp(iv, iv, 0x114, 0xF, 0xF, false);
    x = fmaxf(x, __int_as_float(t)); iv = __float_as_int(x);
    t = __builtin_amdgcn_update_dpp(iv, iv, 0x118, 0xF, 0xF, false);
    x = fmaxf(x, __int_as_float(t)); iv = __float_as_int(x);
    t = __builtin_amdgcn_update_dpp(iv, iv, 0x142, 0xA, 0xF, false);
    x = fmaxf(x, __int_as_float(t)); iv = __float_as_int(x);
    t = __builtin_amdgcn_update_dpp(iv, iv, 0x143, 0xC, 0xF, false);
    x = fmaxf(x, __int_as_float(t));
    return x;
}

__device__ __forceinline__ float wave_sum63(float x) {
    int t;
    t = __builtin_amdgcn_update_dpp(0, __float_as_int(x), 0x111, 0xF, 0xF, true);
    x += __int_as_float(t);
    t = __builtin_amdgcn_update_dpp(0, __float_as_int(x), 0x112, 0xF, 0xF, true);
    x += __int_as_float(t);
    t = __builtin_amdgcn_update_dpp(0, __float_as_int(x), 0x114, 0xF, 0xF, true);
    x += __int_as_float(t);
    t = __builtin_amdgcn_update_dpp(0, __float_as_int(x), 0x118, 0xF, 0xF, true);
    x += __int_as_float(t);
    t = __builtin_amdgcn_update_dpp(0, __float_as_int(x), 0x142, 0xA, 0xF, true);
    x += __int_as_float(t);
    t = __builtin_amdgcn_update_dpp(0, __float_as_int(x), 0x143, 0xC, 0xF, true);
    x += __int_as_float(t);
    return x;
}

__device__ __forceinline__ float rdl63(float v) {
    return __int_as_float(__builtin_amdgcn_readlane(__float_as_int(v), 63));
}

// One block per batch. Waves 1-3 stream y_pred -> lse + fp16 (d1,d3) into a
// 2x[64][64] LDS chunk ring; wave 0 runs the serial alpha recursion per chunk.
__global__ __launch_bounds__(256) void ctc_fused(const int* __restrict__ yt,
                                                 const float* __restrict__ yp,
                                                 float* __restrict__ loss) {
    constexpr int T = 512, C = 128, L = 128;
    constexpr int CH = 64;
    const int b    = blockIdx.x;
    const int tid  = threadIdx.x;
    const int w    = tid >> 6;
    const int lane = tid & 63;

    __shared__ __half2 gbuf[2][CH][64];   // 32 KB
    __shared__ float   Af[257];
    __shared__ float   accS[4];

    const float* xpb = yp + (size_t)b * T * C;

    // per-lane label classes (lane l owns extended states 4l..4l+3)
    const int2 cc = *reinterpret_cast<const int2*>(yt + b * L + 2 * lane);
    const int c1 = cc.x, c3 = cc.y;
    const int sl1 = c1 >> 1, sh1 = (c1 & 1) << 4;
    const int sl3 = c3 >> 1, sh3 = (c3 & 1) << 4;

    float acc = 0.0f;   // producer: sum of (lse - x_blank) over its rows

    auto produce = [&](int ck) {
        const int sel   = ck & 1;
        const int rbase = (w == 1) ? 0 : (w == 2) ? 21 : 42;
        const int rcnt  = (w == 3) ? 22 : 21;
        const float* src = xpb + ((size_t)ck * CH + rbase) * C + lane * 2;
        float2 v[22];
        #pragma unroll
        for (int i = 0; i < 22; ++i)
            if (i < rcnt) v[i] = *reinterpret_cast<const float2*>(src + i * C);
        #pragma unroll
        for (int i = 0; i < 22; ++i) {
            if (i < rcnt) {
                const float2 vv = v[i];
                const float mall = rdl63(wave_max63(fmaxf(vv.x, vv.y)));
                const float sall = rdl63(wave_sum63(__expf(vv.x - mall) + __expf(vv.y - mall)));
                const float xbv  = rdl63(vv.y);   // class 127 (blank) = lane63.y
                acc += (mall - xbv) + __logf(sall);
                const __half2 hh = __floats2half2_rn(vv.x, vv.y);
                const int hbits = __builtin_bit_cast(int, hh);
                const int g1 = __shfl(hbits, sl1, 64);
                const int g3 = __shfl(hbits, sl3, 64);
                const float x1 = __half2float(__builtin_bit_cast(__half, (unsigned short)(g1 >> sh1)));
                const float x3 = __half2float(__builtin_bit_cast(__half, (unsigned short)(g3 >> sh3)));
                gbuf[sel][rbase + i][lane] = __floats2half2_rn(x1 - xbv, x3 - xbv);
            }
        }
    };

    // consumer state (wave 0): lane l owns s=4l..4l+3; lane63 also s=256 in o4
    float o0 = 0, o1 = 0, o2 = 0, o3 = 0, o4 = 0;
    int   Eacc = 0;
    float sk1 = 0, sk3 = 0;
    int   llen = 0;
    if (w == 0) {
        const int cprev = __shfl_up(c3, 1, 64);
        sk1 = (lane > 0 && c1 != cprev) ? 1.0f : 0.0f;
        sk3 = (c3 != c1) ? 1.0f : 0.0f;
        llen = __popcll(__ballot(c1 != 0)) + __popcll(__ballot(c3 != 0));
    }

#define RENORM()                                                               \
    {                                                                          \
        float mr = fmaxf(fmaxf(fmaxf(o0, o1), fmaxf(o2, o3)), o4);             \
        const float mru = rdl63(wave_max63(mr));                               \
        const int ie = (__float_as_int(mru) >> 23) & 0xFF;                     \
        const float sc = __int_as_float((253 - ie) << 23);                     \
        o0 *= sc; o1 *= sc; o2 *= sc; o3 *= sc; o4 *= sc;                      \
        Eacc += ie - 126;                                                      \
    }

#define CSTEP(bits_, rn_)                                                      \
    {                                                                          \
        const float2 dd = __half22float2(__builtin_bit_cast(__half2, (bits_)));\
        const float e1 = __expf(dd.x);                                         \
        const float e3 = __expf(dd.y);                                         \
        const float pm = shr1(o3, 0.0f);                                       \
        const float n0 = o0 + pm;                                              \
        const float n1 = (o1 + o0 + sk1 * pm) * e1;                            \
        const float n2 = o2 + o1;                                              \
        const float n3 = (o3 + o2 + sk3 * o1) * e3;                            \
        o4 += o3;                                                              \
        o0 = n0; o1 = n1; o2 = n2; o3 = n3;                                    \
        if (rn_) RENORM();                                                     \
    }

    auto consume = [&](const __half2 (*gb)[64], bool first) {
        int A[8], Bv[8];
        #pragma unroll
        for (int j = 0; j < 8; ++j) A[j] = __builtin_bit_cast(int, gb[j][lane]);
        #pragma unroll
        for (int j = 0; j < 8; ++j) Bv[j] = __builtin_bit_cast(int, gb[8 + j][lane]);
        if (first) {   // t=0 init: beta_0 = exp(alpha_0 - x_0[blank])
            const float2 d0 = __half22float2(__builtin_bit_cast(__half2, A[0]));
            o0 = (lane == 0) ? 1.0f : 0.0f;
            o1 = (lane == 0) ? __expf(d0.x) : 0.0f;
            o2 = 0.0f; o3 = 0.0f; o4 = 0.0f;
        } else {
            CSTEP(A[0], true);                       // t = 64k -> renorm
        }
        #pragma unroll
        for (int j = 1; j < 8; ++j) CSTEP(A[j], false);
        #pragma unroll
        for (int j = 0; j < 8; ++j) A[j] = __builtin_bit_cast(int, gb[16 + j][lane]);
        #pragma unroll
        for (int j = 0; j < 8; ++j) CSTEP(Bv[j], false);   // rows 8..15
        #pragma unroll
        for (int j = 0; j < 8; ++j) Bv[j] = __builtin_bit_cast(int, gb[24 + j][lane]);
        #pragma unroll
        for (int j = 0; j < 8; ++j) CSTEP(A[j], false);    // rows 16..23
        #pragma unroll
        for (int j = 0; j < 8; ++j) A[j] = __builtin_bit_cast(int, gb[32 + j][lane]);
        #pragma unroll
        for (int j = 0; j < 8; ++j) CSTEP(Bv[j], false);   // rows 24..31
        #pragma unroll
        for (int j = 0; j < 8; ++j) Bv[j] = __builtin_bit_cast(int, gb[40 + j][lane]);
        CSTEP(A[0], true);                                  // row 32 -> renorm
        #pragma unroll
        for (int j = 1; j < 8; ++j) CSTEP(A[j], false);    // rows 33..39
        #pragma unroll
        for (int j = 0; j < 8; ++j) A[j] = __builtin_bit_cast(int, gb[48 + j][lane]);
        #pragma unroll
        for (int j = 0; j < 8; ++j) CSTEP(Bv[j], false);   // rows 40..47
        #pragma unroll
        for (int j = 0; j < 8; ++j) Bv[j] = __builtin_bit_cast(int, gb[56 + j][lane]);
        #pragma unroll
        for (int j = 0; j < 8; ++j) CSTEP(A[j], false);    // rows 48..55
        #pragma unroll
        for (int j = 0; j < 8; ++j) CSTEP(Bv[j], false);   // rows 56..63
    };

    // ---- schedule: produce(k+1) overlaps consume(k); one barrier per chunk
    if (w != 0) produce(0);
    __syncthreads();
    if (w != 0) produce(1); else consume(gbuf[0], true);
    __syncthreads();
    for (int k = 1; k < 8; ++k) {
        if (w != 0) { if (k < 7) produce(k + 1); }
        else        consume(gbuf[k & 1], false);
        __syncthreads();
    }

    // epilogue
    if (w == 0) {
        Af[4 * lane + 0] = o0; Af[4 * lane + 1] = o1;
        Af[4 * lane + 2] = o2; Af[4 * lane + 3] = o3;
        if (lane == 63) Af[256] = o4;
    } else if (lane == 0) {
        accS[w] = acc;
    }
    __syncthreads();
    if (tid == 0) {
        const float fa = Af[2 * llen];
        const float fb = Af[2 * llen - 1];
        const float ls = (accS[1] + accS[2]) + accS[3];
        loss[b] = -(__logf(fa + fb) + (float)Eacc * LN2F - ls);
    }
#undef CSTEP
#undef RENORM
}

// deterministic mean over B=256 losses
__global__ __launch_bounds__(256) void finalize(const float* __restrict__ loss,
                                                float* __restrict__ out) {
    __shared__ float red[256];
    const int tid = threadIdx.x;
    red[tid] = loss[tid];
    __syncthreads();
    for (int off = 128; off > 0; off >>= 1) {
        if (tid < off) red[tid] += red[tid + off];
        __syncthreads();
    }
    if (tid == 0) out[0] = red[0] * (1.0f / 256.0f);
}

extern "C" void kernel_launch(void* const* d_in, const int* in_sizes, int n_in,
                              void* d_out, int out_size, void* d_ws, size_t ws_size,
                              hipStream_t stream) {
    constexpr int B = 256;
    const int*   y_true = (const int*)d_in[0];
    const float* y_pred = (const float*)d_in[1];
    float* out  = (float*)d_out;
    float* lossbuf = (float*)d_ws;   // B floats

    ctc_fused<<<B, 256, 0, stream>>>(y_true, y_pred, lossbuf);
    finalize<<<1, 256, 0, stream>>>(lossbuf, out);
}